// Round 10
// baseline (11752.960 us; speedup 1.0000x reference)
//
#include <hip/hip_runtime.h>
#include <math.h>

#define TT 256
#define BB 128
#define II 512
#define HH 1024
#define NCLS 1000
#define NBLK 32            // 4 row-groups x 8 col-groups
#define NRG 4              // row groups (32 batch rows each)
#define NCG 8              // col groups (128 h-cols each)

typedef __bf16 bf16;
typedef bf16 bf16x8 __attribute__((ext_vector_type(8)));
typedef float f32x4 __attribute__((ext_vector_type(4)));
typedef int i32x4 __attribute__((ext_vector_type(4)));

#define AT_LD_I32(p) __hip_atomic_load((p), __ATOMIC_RELAXED, __HIP_MEMORY_SCOPE_AGENT)

// ---------------- ws layout (bytes) ----------------
#define OFF_WHP  0u            // [g*1024+h][k] g in {f,i,o}: 3*1024*1024*2 = 6,291,456
#define OFF_LG   0u            // logits alias (dead after scan)
#define OFF_WXP  6291456u      // [g*1024+h][k] g in {f,i,o,c}: 4*1024*512*2 = 4,194,304
#define OFF_BIAS 10485760u     // 16,384
#define OFF_HB0  10502144u     // 262,144  h ping, row-major [b][1024] bf16
#define OFF_HB1  10764288u     // 262,144  h pong
#define OFF_CNT  11288576u     // 4 monotonic group counters, 128B apart
#define OFF_XT   11321600u     // 33,554,432  xT[t][b][i] bf16
#define WS_BIG   44876032u

#define LDS_H    65536         // h tile [32 rows][2048 B], XOR-swizzled
#define LDS_GD   65536         // offset of gdone[256]
#define LDS_GF   66560         // offset of gflag
#define LDS_TOTAL 66624

// ---------------- init: zero counters ----------------
__global__ void init_state(int* __restrict__ cnt) {
    int idx = blockIdx.x * 256 + threadIdx.x;
    if (idx < NRG * 32) cnt[idx] = 0;
}

// ---------------- pack W[k][1024] fp32 -> dst[h][K] bf16 (transpose) ----------------
__global__ void pack_wt(const float* __restrict__ src, bf16* __restrict__ dst, int K) {
    int nk = K >> 6;
    int kt = blockIdx.x % nk, ht = blockIdx.x / nk;
    __shared__ bf16 tile[64][72];
    int tid = threadIdx.x;
    for (int i = tid; i < 4096; i += 256) {
        int kr = i >> 6, hc = i & 63;
        tile[kr][hc] = (bf16)src[(size_t)(kt * 64 + kr) * HH + ht * 64 + hc];
    }
    __syncthreads();
    for (int i = tid; i < 4096; i += 256) {
        int hc = i >> 6, kr = i & 63;
        dst[(size_t)(ht * 64 + hc) * K + kt * 64 + kr] = tile[kr][hc];
    }
}

__global__ void pack_bias(const float* __restrict__ bf_, const float* __restrict__ bi_,
                          const float* __restrict__ bo_, const float* __restrict__ bc_,
                          float* __restrict__ bias) {
    int i = blockIdx.x * 256 + threadIdx.x;
    if (i < 4 * HH) {
        int g = i >> 10, hn = i & 1023;
        const float* b = (g == 0) ? bf_ : (g == 1) ? bi_ : (g == 2) ? bo_ : bc_;
        bias[i] = b[hn];
    }
}

// ---------------- x[b][t][i] fp32 -> xT[t][b][i] bf16 ----------------
__global__ void conv_xT(const float* __restrict__ x, bf16* __restrict__ xT) {
    size_t o = ((size_t)blockIdx.x * 256 + threadIdx.x) * 8;
    int t = (int)(o >> 16);
    int rem = (int)(o & 65535);
    int b = rem >> 9, i = rem & 511;
    const float* s = x + ((size_t)b * TT + t) * II + i;
    float4 f0 = *(const float4*)(s);
    float4 f1 = *(const float4*)(s + 4);
    bf16x8 v;
    v[0]=(bf16)f0.x; v[1]=(bf16)f0.y; v[2]=(bf16)f0.z; v[3]=(bf16)f0.w;
    v[4]=(bf16)f1.x; v[5]=(bf16)f1.y; v[6]=(bf16)f1.z; v[7]=(bf16)f1.w;
    *(bf16x8*)(xT + o) = v;
}

__device__ __forceinline__ float sigm(float x) { return 1.0f / (1.0f + __expf(-x)); }
__device__ __forceinline__ float tanh_f(float x) {
    float e = __expf(-2.0f * fabsf(x));
    float t = (1.0f - e) / (1.0f + e);
    return copysignf(t, x);
}

__device__ __forceinline__ i32x4 ld16c(const void* p) {   // coherent (L3) 16B load
    i32x4 d;
    asm volatile("global_load_dwordx4 %0, %1, off sc0 sc1" : "=v"(d) : "v"(p) : "memory");
    return d;
}
#define WAITV0() do { asm volatile("s_waitcnt vmcnt(0)" ::: "memory"); \
                      __builtin_amdgcn_sched_barrier(0); } while (0)

// ---------------- persistent recurrent kernel: 2-D partition ----------------
// 32 blocks x 512 threads (8 waves). Block (r,c) = (bid>>3, bid&7): batch rows
// [32r,32r+32) x h-cols [128c,128c+128), all 4 gates (wave w owns 16 cols,
// tau 0-3 = f,i,o,c) -> pointwise thread-local, c in regs. Barrier fan-in: the
// 8 blocks of row-group r share ONE monotonic counter; 4 groups fully
// independent (rows never couple). h staged to LDS once per block (coop sc1
// loads, XOR swizzle). Weights stream from L2 (bid%8=c keeps the col-slice on
// one XCD under round-robin; read-only so placement affects perf only).
template<bool XB>
__global__ __launch_bounds__(512) void lstm_persist(
    const float* __restrict__ xf, const bf16* __restrict__ xT,
    const bf16* __restrict__ WhP, const bf16* __restrict__ WxP,
    const float* __restrict__ bias,
    bf16* __restrict__ hb0, bf16* __restrict__ hb1, int* __restrict__ cnt) {
    extern __shared__ char lds[];
    int* gdone = (int*)(lds + LDS_GD);             // [256] per-step wave counters
    volatile int* gflag = (volatile int*)(lds + LDS_GF);
    const int tid = threadIdx.x, w = tid >> 6, lane = tid & 63;
    const int bid = blockIdx.x, r = bid >> 3, c = bid & 7;
    const int lr = lane & 15, lkq = lane >> 4, lk = lkq * 8, rb = lkq * 4;
    const int RB = r * 32;                         // batch-row base
    const int CBw = c * 128 + w * 16;              // this wave's h-col base

    for (int i = tid; i < 256; i += 512) gdone[i] = 0;
    if (tid == 0) gflag[0] = 0;
    __syncthreads();

    const float bb0 = bias[0 * HH + CBw + lr];
    const float bb1 = bias[1 * HH + CBw + lr];
    const float bb2 = bias[2 * HH + CBw + lr];
    const float bb3 = bias[3 * HH + CBw + lr];
    float creg[2][4] = {};
    const bf16* wxb0 = WxP + (size_t)(0 * HH + CBw + lr) * 512;
    const bf16* wxb1 = WxP + (size_t)(1 * HH + CBw + lr) * 512;
    const bf16* wxb2 = WxP + (size_t)(2 * HH + CBw + lr) * 512;
    const bf16* wxb3 = WxP + (size_t)(3 * HH + CBw + lr) * 512;
    const bf16* whb0 = WhP + (size_t)(0 * HH + CBw + lr) * 1024;
    const bf16* whb1 = WhP + (size_t)(1 * HH + CBw + lr) * 1024;
    const bf16* whb2 = WhP + (size_t)(2 * HH + CBw + lr) * 1024;
    const int* cw = cnt + r * 32;                  // group counter (128B apart)

    for (int t = 0; t < TT; ++t) {
        f32x4 acc[2][4] = {};                      // [m][tau]

        // ---- x-part (K=512), independent of h_t: hides detect latency ----
        const bf16* xa = XB ? (xT + ((size_t)t * BB + RB) * II) : nullptr;
        #pragma unroll 4
        for (int kk = 0; kk < 16; ++kk) {
            const int k0 = kk * 32 + lk;
            bf16x8 a0, a1;
            if (XB) {
                a0 = *(const bf16x8*)(xa + (size_t)lr * II + k0);
                a1 = *(const bf16x8*)(xa + (size_t)(16 + lr) * II + k0);
            } else {
                const float* s0 = xf + ((size_t)(RB + lr) * TT + t) * II + k0;
                const float* s1 = xf + ((size_t)(RB + 16 + lr) * TT + t) * II + k0;
                float4 f0 = *(const float4*)s0, f1 = *(const float4*)(s0 + 4);
                float4 g0 = *(const float4*)s1, g1 = *(const float4*)(s1 + 4);
                a0[0]=(bf16)f0.x; a0[1]=(bf16)f0.y; a0[2]=(bf16)f0.z; a0[3]=(bf16)f0.w;
                a0[4]=(bf16)f1.x; a0[5]=(bf16)f1.y; a0[6]=(bf16)f1.z; a0[7]=(bf16)f1.w;
                a1[0]=(bf16)g0.x; a1[1]=(bf16)g0.y; a1[2]=(bf16)g0.z; a1[3]=(bf16)g0.w;
                a1[4]=(bf16)g1.x; a1[5]=(bf16)g1.y; a1[6]=(bf16)g1.z; a1[7]=(bf16)g1.w;
            }
            bf16x8 b0 = *(const bf16x8*)(wxb0 + k0);
            bf16x8 b1 = *(const bf16x8*)(wxb1 + k0);
            bf16x8 b2 = *(const bf16x8*)(wxb2 + k0);
            bf16x8 b3 = *(const bf16x8*)(wxb3 + k0);
            acc[0][0] = __builtin_amdgcn_mfma_f32_16x16x32_bf16(a0, b0, acc[0][0], 0, 0, 0);
            acc[1][0] = __builtin_amdgcn_mfma_f32_16x16x32_bf16(a1, b0, acc[1][0], 0, 0, 0);
            acc[0][1] = __builtin_amdgcn_mfma_f32_16x16x32_bf16(a0, b1, acc[0][1], 0, 0, 0);
            acc[1][1] = __builtin_amdgcn_mfma_f32_16x16x32_bf16(a1, b1, acc[1][1], 0, 0, 0);
            acc[0][2] = __builtin_amdgcn_mfma_f32_16x16x32_bf16(a0, b2, acc[0][2], 0, 0, 0);
            acc[1][2] = __builtin_amdgcn_mfma_f32_16x16x32_bf16(a1, b2, acc[1][2], 0, 0, 0);
            acc[0][3] = __builtin_amdgcn_mfma_f32_16x16x32_bf16(a0, b3, acc[0][3], 0, 0, 0);
            acc[1][3] = __builtin_amdgcn_mfma_f32_16x16x32_bf16(a1, b3, acc[1][3], 0, 0, 0);
        }

        if (t > 0) {                               // t=0: h0 = 0, skip
            // ---- wait: single poller wave, one counter word, LDS broadcast ----
            if (w == 0) {
                const int need = 8 * t;
                while (AT_LD_I32(cw) < need) __builtin_amdgcn_s_sleep(2);
                asm volatile("" ::: "memory");
                gflag[0] = t;
            } else {
                while (gflag[0] < t) __builtin_amdgcn_s_sleep(1);
            }
            asm volatile("s_waitcnt vmcnt(0) lgkmcnt(0)" ::: "memory");
            __builtin_amdgcn_sched_barrier(0);

            // ---- coop-load h rows [RB,RB+32) (64KB, sc1) -> LDS swizzled ----
            const char* hb = (const char*)((t & 1) ? hb1 : hb0) + (size_t)RB * 2048;
            i32x4 hv[8];
            #pragma unroll
            for (int q = 0; q < 8; ++q)
                hv[q] = ld16c(hb + (q * 512 + tid) * 16);
            WAITV0();
            #pragma unroll
            for (int q = 0; q < 8; ++q) {
                int idx = q * 512 + tid;
                int row = idx >> 7, kb = (idx & 127) * 16;
                *(i32x4*)(lds + ((row * 2048 + kb) ^ ((row & 7) << 4))) = hv[q];
            }
            __syncthreads();

            // ---- h-part (K=1024): A from LDS, B = WhP (f,i,o) from L2 ----
            const int sw0 = (lr & 7) << 4, sw1 = ((16 + lr) & 7) << 4;
            #pragma unroll 4
            for (int kk = 0; kk < 32; ++kk) {
                const int k0 = kk * 32 + lk;
                bf16x8 a0 = *(const bf16x8*)(lds + ((lr * 2048 + k0 * 2) ^ sw0));
                bf16x8 a1 = *(const bf16x8*)(lds + (((16 + lr) * 2048 + k0 * 2) ^ sw1));
                bf16x8 b0 = *(const bf16x8*)(whb0 + k0);
                bf16x8 b1 = *(const bf16x8*)(whb1 + k0);
                bf16x8 b2 = *(const bf16x8*)(whb2 + k0);
                acc[0][0] = __builtin_amdgcn_mfma_f32_16x16x32_bf16(a0, b0, acc[0][0], 0, 0, 0);
                acc[1][0] = __builtin_amdgcn_mfma_f32_16x16x32_bf16(a1, b0, acc[1][0], 0, 0, 0);
                acc[0][1] = __builtin_amdgcn_mfma_f32_16x16x32_bf16(a0, b1, acc[0][1], 0, 0, 0);
                acc[1][1] = __builtin_amdgcn_mfma_f32_16x16x32_bf16(a1, b1, acc[1][1], 0, 0, 0);
                acc[0][2] = __builtin_amdgcn_mfma_f32_16x16x32_bf16(a0, b2, acc[0][2], 0, 0, 0);
                acc[1][2] = __builtin_amdgcn_mfma_f32_16x16x32_bf16(a1, b2, acc[1][2], 0, 0, 0);
            }
        }

        // ---- pointwise (thread-local), h -> coherent dword stores ----
        bf16* ho = (t & 1) ? hb0 : hb1;
        #pragma unroll
        for (int m = 0; m < 2; ++m) {
            #pragma unroll
            for (int j = 0; j < 4; ++j) {
                const int row = RB + m * 16 + rb + j;
                float pf = acc[m][0][j] + bb0;
                float pi = acc[m][1][j] + bb1;
                float po = acc[m][2][j] + bb2;
                float pc = acc[m][3][j] + bb3;
                float fg = sigm(pf), ig = sigm(pi), og = sigm(po);
                float cn = tanh_f(pc) * ig + creg[m][j] * fg;
                creg[m][j] = cn;
                union { bf16 h; unsigned short u; } cv;
                cv.h = (bf16)(tanh_f(cn) * og);
                unsigned int mine  = (unsigned int)cv.u;
                unsigned int other = (unsigned int)__shfl_xor((int)mine, 1);
                if (!(lane & 1)) {
                    unsigned int word = mine | (other << 16);
                    bf16* hp = ho + (size_t)row * HH + (CBw + (lr & 14));
                    asm volatile("global_store_dword %0, %1, off sc0 sc1"
                                 :: "v"(hp), "v"(word) : "memory");
                }
            }
        }
        asm volatile("s_waitcnt vmcnt(0)" ::: "memory");   // h at coherence point
        __builtin_amdgcn_sched_barrier(0);
        if (lane == 0) {
            int old = atomicAdd(&gdone[t], 1);
            if (old == 7)                          // last wave of this block
                atomicAdd((int*)cw, 1);            // device-scope, monotonic
        }
    }
}

// ---------------- head: logits = h @ W_ph + b_p ----------------
__global__ __launch_bounds__(256) void logits_kernel(
    const bf16* __restrict__ h, const float* __restrict__ Wp,
    const float* __restrict__ bp, float* __restrict__ out) {
    const int tid = threadIdx.x;
    const int r0  = blockIdx.x * 8;
    __shared__ float hs[8][HH];
    for (int i = tid; i < 8 * HH; i += 256)
        hs[i >> 10][i & 1023] = (float)h[(size_t)(r0 + (i >> 10)) * HH + (i & 1023)];
    __syncthreads();
    float acc[8][4] = {};
    for (int k = 0; k < HH; ++k) {
        float w[4];
        #pragma unroll
        for (int m = 0; m < 4; ++m) {
            int cc = tid + 256 * m;
            w[m] = (cc < NCLS) ? Wp[(size_t)k * NCLS + cc] : 0.0f;
        }
        #pragma unroll
        for (int r = 0; r < 8; ++r) {
            float hv = hs[r][k];
            #pragma unroll
            for (int m = 0; m < 4; ++m) acc[r][m] += hv * w[m];
        }
    }
    #pragma unroll
    for (int r = 0; r < 8; ++r) {
        #pragma unroll
        for (int m = 0; m < 4; ++m) {
            int cc = tid + 256 * m;
            if (cc < NCLS) out[(size_t)(r0 + r) * NCLS + cc] = acc[r][m] + bp[cc];
        }
    }
}

// ---------------- softmax over C=1000 per row ----------------
__global__ __launch_bounds__(256) void softmax_kernel(const float* __restrict__ logits,
                                                      float* __restrict__ out) {
    const int b = blockIdx.x, tid = threadIdx.x;
    __shared__ float red[256];
    float v[4];
    float mx = -1e30f;
    #pragma unroll
    for (int m = 0; m < 4; ++m) {
        int cc = tid + 256 * m;
        v[m] = (cc < NCLS) ? logits[(size_t)b * NCLS + cc] : -1e30f;
        mx = fmaxf(mx, v[m]);
    }
    red[tid] = mx; __syncthreads();
    for (int s = 128; s > 0; s >>= 1) {
        if (tid < s) red[tid] = fmaxf(red[tid], red[tid + s]);
        __syncthreads();
    }
    mx = red[0]; __syncthreads();
    float sum = 0.0f;
    #pragma unroll
    for (int m = 0; m < 4; ++m) {
        int cc = tid + 256 * m;
        if (cc < NCLS) { v[m] = __expf(v[m] - mx); sum += v[m]; }
    }
    red[tid] = sum; __syncthreads();
    for (int s = 128; s > 0; s >>= 1) {
        if (tid < s) red[tid] += red[tid + s];
        __syncthreads();
    }
    float inv = 1.0f / red[0];
    #pragma unroll
    for (int m = 0; m < 4; ++m) {
        int cc = tid + 256 * m;
        if (cc < NCLS) out[(size_t)b * NCLS + cc] = v[m] * inv;
    }
}

extern "C" void kernel_launch(void* const* d_in, const int* in_sizes, int n_in,
                              void* d_out, int out_size, void* d_ws, size_t ws_size,
                              hipStream_t stream) {
    const float* x   = (const float*)d_in[0];
    const float* Wfx = (const float*)d_in[1];
    const float* Wfh = (const float*)d_in[2];
    const float* bf_ = (const float*)d_in[3];
    const float* Wix = (const float*)d_in[4];
    const float* Wih = (const float*)d_in[5];
    const float* bi_ = (const float*)d_in[6];
    const float* Wox = (const float*)d_in[7];
    const float* Woh = (const float*)d_in[8];
    const float* bo_ = (const float*)d_in[9];
    const float* Wcx = (const float*)d_in[10];
    const float* bc_ = (const float*)d_in[11];
    const float* Wp  = (const float*)d_in[12];
    const float* bp  = (const float*)d_in[13];

    char* ws = (char*)d_ws;
    bf16*  WhP  = (bf16*)(ws + OFF_WHP);
    bf16*  WxP  = (bf16*)(ws + OFF_WXP);
    float* bias = (float*)(ws + OFF_BIAS);
    bf16*  hb0  = (bf16*)(ws + OFF_HB0);
    bf16*  hb1  = (bf16*)(ws + OFF_HB1);
    int*   cnt  = (int*)(ws + OFF_CNT);
    bf16*  xT   = (bf16*)(ws + OFF_XT);
    float* lg   = (float*)(ws + OFF_LG);   // aliases WhP (dead after scan)

    (void)hipFuncSetAttribute((const void*)lstm_persist<true>,
                              hipFuncAttributeMaxDynamicSharedMemorySize, LDS_TOTAL);
    (void)hipFuncSetAttribute((const void*)lstm_persist<false>,
                              hipFuncAttributeMaxDynamicSharedMemorySize, LDS_TOTAL);

    init_state<<<1, 256, 0, stream>>>(cnt);
    // Wh{f,i,o} -> WhP[g*1024+h][1024]
    pack_wt<<<256, 256, 0, stream>>>(Wfh, WhP + (size_t)0 * HH * 1024, 1024);
    pack_wt<<<256, 256, 0, stream>>>(Wih, WhP + (size_t)1 * HH * 1024, 1024);
    pack_wt<<<256, 256, 0, stream>>>(Woh, WhP + (size_t)2 * HH * 1024, 1024);
    // Wx{f,i,o,c} -> WxP[g*1024+h][512]
    pack_wt<<<128, 256, 0, stream>>>(Wfx, WxP + (size_t)0 * HH * 512, 512);
    pack_wt<<<128, 256, 0, stream>>>(Wix, WxP + (size_t)1 * HH * 512, 512);
    pack_wt<<<128, 256, 0, stream>>>(Wox, WxP + (size_t)2 * HH * 512, 512);
    pack_wt<<<128, 256, 0, stream>>>(Wcx, WxP + (size_t)3 * HH * 512, 512);
    pack_bias<<<16, 256, 0, stream>>>(bf_, bi_, bo_, bc_, bias);

    const bool big = (ws_size >= (size_t)WS_BIG);
    if (big) {
        conv_xT<<<(BB * TT * II) / (8 * 256), 256, 0, stream>>>(x, xT);
        lstm_persist<true><<<NBLK, 512, LDS_TOTAL, stream>>>(x, xT, WhP, WxP, bias,
                                                             hb0, hb1, cnt);
    } else {
        lstm_persist<false><<<NBLK, 512, LDS_TOTAL, stream>>>(x, xT, WhP, WxP, bias,
                                                              hb0, hb1, cnt);
    }

    // t=255 writes hb0 -> final h in hb0 (kernel boundary = coherence for reader)
    logits_kernel<<<BB / 8, 256, 0, stream>>>(hb0, Wp, bp, lg);
    softmax_kernel<<<BB, 256, 0, stream>>>(lg, (float*)d_out);
}

// Round 11
// 3091.933 us; speedup vs baseline: 3.8012x; 3.8012x over previous
//
#include <hip/hip_runtime.h>
#include <math.h>

#define TT 256
#define BB 128
#define II 512
#define HH 1024
#define NCLS 1000
#define NBLK 128           // 2 row-groups x 64 col-groups

typedef __bf16 bf16;
typedef bf16 bf16x8 __attribute__((ext_vector_type(8)));
typedef float f32x4 __attribute__((ext_vector_type(4)));
typedef int i32x4 __attribute__((ext_vector_type(4)));

#define AT_LD_I32(p) __hip_atomic_load((p), __ATOMIC_RELAXED, __HIP_MEMORY_SCOPE_AGENT)

// ---------------- ws layout (bytes) ----------------
#define OFF_WHPK 0u            // [s][g*16+c][1024] g in {f,i,o}: 6,291,456 (dead after scan)
#define OFF_LG   0u            // logits alias
#define OFF_WXPK 6291456u      // [s][g*16+c][512] g in {f,i,o,c}: 4,194,304
#define OFF_BIAS 10485760u     // 16,384
#define OFF_HB0  10502144u     // 262,144  h ping, row-major [b][1024] bf16
#define OFF_HB1  10764288u     // 262,144  h pong
#define OFF_CNT  11026432u     // 16 striped counters x 128B = 2,048
#define OFF_XT   11028480u     // 33,554,432  xT[t][b][i] bf16
#define WS_BIG   44582912u

#define LDS_WX    98304        // Wx{f,i,o} region offset (48 rows x 1024B)
#define LDS_TOTAL 147456       // 96KB Wh + 48KB Wx -> 1 block/CU, capacity 256 >= 128

// ---------------- init: zero striped counters ----------------
__global__ void init_state(int* __restrict__ cnt) {
    int idx = blockIdx.x * 256 + threadIdx.x;
    if (idx < 512) cnt[idx] = 0;
}

// ---------------- pack W_h -> WhPK[s][g*16+c][k], g in {f,i,o} (R8-proven) ----------------
__global__ void pack_wh(const float* __restrict__ Wfh, const float* __restrict__ Wih,
                        const float* __restrict__ Woh, bf16* __restrict__ WhPK) {
    int blk = blockIdx.x;                 // 3 * 16 * 16
    int g = blk / 256, rem = blk % 256;
    int ht = rem / 16, kt = rem % 16;
    const float* src = (g == 0) ? Wfh : (g == 1) ? Wih : Woh;
    __shared__ bf16 tile[64][72];
    int tid = threadIdx.x;
    for (int i = tid; i < 4096; i += 256) {
        int kr = i >> 6, hc = i & 63;
        tile[kr][hc] = (bf16)src[(size_t)(kt * 64 + kr) * HH + ht * 64 + hc];
    }
    __syncthreads();
    for (int i = tid; i < 4096; i += 256) {
        int hc = i >> 6, kr = i & 63;
        int h = ht * 64 + hc, s = h >> 4, c = h & 15;
        WhPK[((size_t)s * 48 + g * 16 + c) * 1024 + kt * 64 + kr] = tile[kr][hc];
    }
}

// ---------------- pack W_x -> WxPK[s][g*16+c][k], g in {f,i,o,c} (R8-proven) ----------------
__global__ void pack_wx(const float* __restrict__ Wfx, const float* __restrict__ Wix,
                        const float* __restrict__ Wox, const float* __restrict__ Wcx,
                        bf16* __restrict__ WxPK) {
    int blk = blockIdx.x;                 // 4 * 16 * 8
    int g = blk / 128, rem = blk % 128;
    int ht = rem / 8, kt = rem % 8;
    const float* src = (g == 0) ? Wfx : (g == 1) ? Wix : (g == 2) ? Wox : Wcx;
    __shared__ bf16 tile[64][72];
    int tid = threadIdx.x;
    for (int i = tid; i < 4096; i += 256) {
        int kr = i >> 6, hc = i & 63;
        tile[kr][hc] = (bf16)src[(size_t)(kt * 64 + kr) * HH + ht * 64 + hc];
    }
    __syncthreads();
    for (int i = tid; i < 4096; i += 256) {
        int hc = i >> 6, kr = i & 63;
        int h = ht * 64 + hc, s = h >> 4, c = h & 15;
        WxPK[((size_t)s * 64 + g * 16 + c) * 512 + kt * 64 + kr] = tile[kr][hc];
    }
}

__global__ void pack_bias(const float* __restrict__ bf_, const float* __restrict__ bi_,
                          const float* __restrict__ bo_, const float* __restrict__ bc_,
                          float* __restrict__ bias) {
    int i = blockIdx.x * 256 + threadIdx.x;
    if (i < 4 * HH) {
        int g = i >> 10, hn = i & 1023;
        const float* b = (g == 0) ? bf_ : (g == 1) ? bi_ : (g == 2) ? bo_ : bc_;
        bias[i] = b[hn];
    }
}

// ---------------- x[b][t][i] fp32 -> xT[t][b][i] bf16 ----------------
__global__ void conv_xT(const float* __restrict__ x, bf16* __restrict__ xT) {
    size_t o = ((size_t)blockIdx.x * 256 + threadIdx.x) * 8;
    int t = (int)(o >> 16);
    int rem = (int)(o & 65535);
    int b = rem >> 9, i = rem & 511;
    const float* s = x + ((size_t)b * TT + t) * II + i;
    float4 f0 = *(const float4*)(s);
    float4 f1 = *(const float4*)(s + 4);
    bf16x8 v;
    v[0]=(bf16)f0.x; v[1]=(bf16)f0.y; v[2]=(bf16)f0.z; v[3]=(bf16)f0.w;
    v[4]=(bf16)f1.x; v[5]=(bf16)f1.y; v[6]=(bf16)f1.z; v[7]=(bf16)f1.w;
    *(bf16x8*)(xT + o) = v;
}

__device__ __forceinline__ float sigm(float x) { return 1.0f / (1.0f + __expf(-x)); }
__device__ __forceinline__ float tanh_f(float x) {
    float e = __expf(-2.0f * fabsf(x));
    float t = (1.0f - e) / (1.0f + e);
    return copysignf(t, x);
}

__device__ __forceinline__ i32x4 ld16c(const void* p) {   // coherent (L3) 16B load
    i32x4 d;
    asm volatile("global_load_dwordx4 %0, %1, off sc0 sc1" : "=v"(d) : "v"(p) : "memory");
    return d;
}
#define WAITVN(n) do { asm volatile("s_waitcnt vmcnt(" #n ")" ::: "memory"); \
                       __builtin_amdgcn_sched_barrier(0); } while (0)

// ---------------- persistent recurrent kernel: weights LDS-resident ----------------
// 128 blocks x 256 threads (4 waves), 144KB LDS, 1 block/CU (capacity 256 >= 128).
// Block (r,c) = (bid&1, bid>>1): batch rows [64r,64r+64) x h-cols [16c,16c+16),
// all 4 gates. Wave w = row-tile w (A loaded once, no duplication); gates =
// inner tau loop, B from XOR-swizzled LDS (Wh f,i,o + Wx f,i,o resident; Wx c
// streamed from L1/L2, 16KB/step). Pointwise thread-local, c-state in regs.
// Row-groups are independent chains; sync per group = 8-way striped monotonic
// counters (R7-proven signal/poll), fan-in 8 per line. Bytes/CU/step ~208KB
// (was 512KB in R7) -- the measured invariant is per-CU load BW x bytes.
template<bool XB>
__global__ __launch_bounds__(256) void lstm_persist(
    const float* __restrict__ xf, const bf16* __restrict__ xT,
    const bf16* __restrict__ WhPK, const bf16* __restrict__ WxPK,
    const float* __restrict__ bias,
    bf16* __restrict__ hb0, bf16* __restrict__ hb1, int* __restrict__ cnt) {
    extern __shared__ char lds[];
    const int tid = threadIdx.x, w = tid >> 6, lane = tid & 63;
    const int bid = blockIdx.x, r = bid & 1, c = bid >> 1;
    const int lr = lane & 15, lkq = lane >> 4, lk = lkq * 8, rb = lkq * 4;
    const int RB = r * 64;                 // batch-row base
    const int CB = c * 16;                 // h-col base

    // ---- stage Wh{f,i,o} (48 rows x 2048B) + Wx{f,i,o} (48 rows x 1024B), swizzled ----
    for (int i = tid; i < 48 * 128; i += 256) {
        int rr = i >> 7, c16 = i & 127;
        bf16x8 v = *(const bf16x8*)(WhPK + ((size_t)c * 48 + rr) * 1024 + c16 * 8);
        *(bf16x8*)(lds + ((rr * 2048 + c16 * 16) ^ ((rr & 15) << 4))) = v;
    }
    for (int i = tid; i < 48 * 64; i += 256) {
        int rr = i >> 6, c16 = i & 63;
        bf16x8 v = *(const bf16x8*)(WxPK + ((size_t)c * 64 + rr) * 512 + c16 * 8);
        *(bf16x8*)(lds + LDS_WX + ((rr * 1024 + c16 * 16) ^ ((rr & 15) << 4))) = v;
    }
    __syncthreads();

    const float bb0 = bias[0 * HH + CB + lr];
    const float bb1 = bias[1 * HH + CB + lr];
    const float bb2 = bias[2 * HH + CB + lr];
    const float bb3 = bias[3 * HH + CB + lr];
    float creg[4] = {};
    const bf16* wxc = WxPK + ((size_t)c * 64 + 48 + lr) * 512;   // c-gate Wx (streamed)
    const int arow = RB + w * 16 + lr;     // this lane's A row (x and h)
    const int* cw = cnt + (r * 8 + (lane & 7)) * 32;

    for (int t = 0; t < TT; ++t) {
        f32x4 acc[4] = {};                 // f,i,o,c

        // ---- x-part (K=512), independent of h_t: hides barrier latency ----
        #pragma unroll 4
        for (int kk = 0; kk < 16; ++kk) {
            const int k0 = kk * 32 + lk;
            bf16x8 a;
            if (XB) {
                a = *(const bf16x8*)(xT + ((size_t)t * BB + arow) * II + k0);
            } else {
                const float* sx = xf + ((size_t)arow * TT + t) * II + k0;
                float4 f0 = *(const float4*)sx, f1 = *(const float4*)(sx + 4);
                a[0]=(bf16)f0.x; a[1]=(bf16)f0.y; a[2]=(bf16)f0.z; a[3]=(bf16)f0.w;
                a[4]=(bf16)f1.x; a[5]=(bf16)f1.y; a[6]=(bf16)f1.z; a[7]=(bf16)f1.w;
            }
            #pragma unroll
            for (int tau = 0; tau < 3; ++tau) {
                const int rr = tau * 16 + lr;
                bf16x8 b = *(const bf16x8*)(lds + LDS_WX + ((rr * 1024 + k0 * 2) ^ ((rr & 15) << 4)));
                acc[tau] = __builtin_amdgcn_mfma_f32_16x16x32_bf16(a, b, acc[tau], 0, 0, 0);
            }
            bf16x8 bc = *(const bf16x8*)(wxc + k0);
            acc[3] = __builtin_amdgcn_mfma_f32_16x16x32_bf16(a, bc, acc[3], 0, 0, 0);
        }

        if (t > 0) {                       // t=0: h0 = 0, skip wait + h-GEMM
            // ---- wait for h_t of my row-group: 8 striped words, lanes 0-7 ----
            if (w == 0) {
                const int need = 8 * t;
                while (true) {
                    int v = AT_LD_I32(cw);
                    if (__all((lane >= 8) || (v >= need))) break;
                    __builtin_amdgcn_s_sleep(4);
                }
            }
            __syncthreads();

            // ---- h-part (K=1024): A via pipelined sc1 loads, B from LDS ----
            const char* hb = (const char*)((t & 1) ? hb1 : hb0)
                             + (size_t)arow * 2048 + lkq * 16;
            #pragma unroll
            for (int p = 0; p < 2; ++p) {
                i32x4 hv[16];
                #pragma unroll
                for (int q = 0; q < 16; ++q)
                    hv[q] = ld16c(hb + (p * 16 + q) * 64);
                #pragma unroll
                for (int half = 0; half < 2; ++half) {
                    if (half == 0) WAITVN(8); else WAITVN(0);
                    #pragma unroll
                    for (int q = half * 8; q < half * 8 + 8; ++q) {
                        const int k0 = (p * 16 + q) * 32 + lk;
                        bf16x8 a = __builtin_bit_cast(bf16x8, hv[q]);
                        #pragma unroll
                        for (int tau = 0; tau < 3; ++tau) {   // c-gate: x-only
                            const int rr = tau * 16 + lr;
                            bf16x8 b = *(const bf16x8*)(lds + ((rr * 2048 + k0 * 2) ^ ((rr & 15) << 4)));
                            acc[tau] = __builtin_amdgcn_mfma_f32_16x16x32_bf16(a, b, acc[tau], 0, 0, 0);
                        }
                    }
                    __builtin_amdgcn_sched_barrier(0);
                }
            }
        }

        // ---- pointwise (thread-local), h_{t+1} -> ping-pong via sc1 stores ----
        bf16* ho = (t & 1) ? hb0 : hb1;
        #pragma unroll
        for (int j = 0; j < 4; ++j) {
            const int row = RB + w * 16 + rb + j;
            float pf = acc[0][j] + bb0;
            float pi = acc[1][j] + bb1;
            float po = acc[2][j] + bb2;
            float pc = acc[3][j] + bb3;
            float fg = sigm(pf), ig = sigm(pi), og = sigm(po);
            float cn = tanh_f(pc) * ig + creg[j] * fg;
            creg[j] = cn;
            union { bf16 h; unsigned short u; } cv;
            cv.h = (bf16)(tanh_f(cn) * og);
            unsigned int mine  = (unsigned int)cv.u;
            unsigned int other = (unsigned int)__shfl_xor((int)mine, 1);
            if (!(lane & 1)) {
                unsigned int word = mine | (other << 16);
                bf16* hp = ho + (size_t)row * HH + (CB + (lr & 14));
                asm volatile("global_store_dword %0, %1, off sc0 sc1"
                             :: "v"(hp), "v"(word) : "memory");
            }
        }
        asm volatile("s_waitcnt vmcnt(0)" ::: "memory");   // h at coherence point
        __builtin_amdgcn_sched_barrier(0);
        __syncthreads();
        if (tid == 0)
            atomicAdd(cnt + (r * 8 + (c & 7)) * 32, 1);    // monotonic stripe
    }
}

// ---------------- head: logits = h @ W_ph + b_p ----------------
__global__ __launch_bounds__(256) void logits_kernel(
    const bf16* __restrict__ h, const float* __restrict__ Wp,
    const float* __restrict__ bp, float* __restrict__ out) {
    const int tid = threadIdx.x;
    const int r0  = blockIdx.x * 8;
    __shared__ float hs[8][HH];
    for (int i = tid; i < 8 * HH; i += 256)
        hs[i >> 10][i & 1023] = (float)h[(size_t)(r0 + (i >> 10)) * HH + (i & 1023)];
    __syncthreads();
    float acc[8][4] = {};
    for (int k = 0; k < HH; ++k) {
        float w[4];
        #pragma unroll
        for (int m = 0; m < 4; ++m) {
            int cc = tid + 256 * m;
            w[m] = (cc < NCLS) ? Wp[(size_t)k * NCLS + cc] : 0.0f;
        }
        #pragma unroll
        for (int r = 0; r < 8; ++r) {
            float hv = hs[r][k];
            #pragma unroll
            for (int m = 0; m < 4; ++m) acc[r][m] += hv * w[m];
        }
    }
    #pragma unroll
    for (int r = 0; r < 8; ++r) {
        #pragma unroll
        for (int m = 0; m < 4; ++m) {
            int cc = tid + 256 * m;
            if (cc < NCLS) out[(size_t)(r0 + r) * NCLS + cc] = acc[r][m] + bp[cc];
        }
    }
}

// ---------------- softmax over C=1000 per row ----------------
__global__ __launch_bounds__(256) void softmax_kernel(const float* __restrict__ logits,
                                                      float* __restrict__ out) {
    const int b = blockIdx.x, tid = threadIdx.x;
    __shared__ float red[256];
    float v[4];
    float mx = -1e30f;
    #pragma unroll
    for (int m = 0; m < 4; ++m) {
        int cc = tid + 256 * m;
        v[m] = (cc < NCLS) ? logits[(size_t)b * NCLS + cc] : -1e30f;
        mx = fmaxf(mx, v[m]);
    }
    red[tid] = mx; __syncthreads();
    for (int s = 128; s > 0; s >>= 1) {
        if (tid < s) red[tid] = fmaxf(red[tid], red[tid + s]);
        __syncthreads();
    }
    mx = red[0]; __syncthreads();
    float sum = 0.0f;
    #pragma unroll
    for (int m = 0; m < 4; ++m) {
        int cc = tid + 256 * m;
        if (cc < NCLS) { v[m] = __expf(v[m] - mx); sum += v[m]; }
    }
    red[tid] = sum; __syncthreads();
    for (int s = 128; s > 0; s >>= 1) {
        if (tid < s) red[tid] += red[tid + s];
        __syncthreads();
    }
    float inv = 1.0f / red[0];
    #pragma unroll
    for (int m = 0; m < 4; ++m) {
        int cc = tid + 256 * m;
        if (cc < NCLS) out[(size_t)b * NCLS + cc] = v[m] * inv;
    }
}

extern "C" void kernel_launch(void* const* d_in, const int* in_sizes, int n_in,
                              void* d_out, int out_size, void* d_ws, size_t ws_size,
                              hipStream_t stream) {
    const float* x   = (const float*)d_in[0];
    const float* Wfx = (const float*)d_in[1];
    const float* Wfh = (const float*)d_in[2];
    const float* bf_ = (const float*)d_in[3];
    const float* Wix = (const float*)d_in[4];
    const float* Wih = (const float*)d_in[5];
    const float* bi_ = (const float*)d_in[6];
    const float* Wox = (const float*)d_in[7];
    const float* Woh = (const float*)d_in[8];
    const float* bo_ = (const float*)d_in[9];
    const float* Wcx = (const float*)d_in[10];
    const float* bc_ = (const float*)d_in[11];
    const float* Wp  = (const float*)d_in[12];
    const float* bp  = (const float*)d_in[13];

    char* ws = (char*)d_ws;
    bf16*  WhPK = (bf16*)(ws + OFF_WHPK);
    bf16*  WxPK = (bf16*)(ws + OFF_WXPK);
    float* bias = (float*)(ws + OFF_BIAS);
    bf16*  hb0  = (bf16*)(ws + OFF_HB0);
    bf16*  hb1  = (bf16*)(ws + OFF_HB1);
    int*   cnt  = (int*)(ws + OFF_CNT);
    bf16*  xT   = (bf16*)(ws + OFF_XT);
    float* lg   = (float*)(ws + OFF_LG);   // aliases WhPK (dead after scan)

    (void)hipFuncSetAttribute((const void*)lstm_persist<true>,
                              hipFuncAttributeMaxDynamicSharedMemorySize, LDS_TOTAL);
    (void)hipFuncSetAttribute((const void*)lstm_persist<false>,
                              hipFuncAttributeMaxDynamicSharedMemorySize, LDS_TOTAL);

    init_state<<<2, 256, 0, stream>>>(cnt);
    pack_wh<<<3 * 16 * 16, 256, 0, stream>>>(Wfh, Wih, Woh, WhPK);
    pack_wx<<<4 * 16 * 8, 256, 0, stream>>>(Wfx, Wix, Wox, Wcx, WxPK);
    pack_bias<<<16, 256, 0, stream>>>(bf_, bi_, bo_, bc_, bias);

    const bool big = (ws_size >= (size_t)WS_BIG);
    if (big) {
        conv_xT<<<(BB * TT * II) / (8 * 256), 256, 0, stream>>>(x, xT);
        lstm_persist<true><<<NBLK, 256, LDS_TOTAL, stream>>>(x, xT, WhPK, WxPK, bias,
                                                             hb0, hb1, cnt);
    } else {
        lstm_persist<false><<<NBLK, 256, LDS_TOTAL, stream>>>(x, xT, WhPK, WxPK, bias,
                                                              hb0, hb1, cnt);
    }

    // t=255 (odd) writes hb0 -> final h in hb0; kernel boundary = coherence
    logits_kernel<<<BB / 8, 256, 0, stream>>>(hb0, Wp, bp, lg);
    softmax_kernel<<<BB, 256, 0, stream>>>(lg, (float*)d_out);
}